// Round 1
// baseline (2518.470 us; speedup 1.0000x reference)
//
#include <hip/hip_runtime.h>
#include <stdint.h>

#define N_NODES 40000
#define M_PAD   40064      // 313 * 128
#define V_DIM   5000
#define K1_PAD  5024       // 157 * 32
#define E_EDGES 1280000
#define B_BATCH 64
#define NCLS    20

typedef __attribute__((ext_vector_type(8))) short bf16x8;
typedef __attribute__((ext_vector_type(4))) float f32x4;

__device__ __forceinline__ unsigned short f2bf(float x) {
    union { float f; unsigned int u; } c; c.f = x;
    unsigned int u = c.u;
    unsigned int r = (u + 0x7FFFu + ((u >> 16) & 1u)) >> 16;  // RNE
    return (unsigned short)r;
}

// ---------------------------------------------------------------------------
// Bt prep: W [K x N] fp32 -> BT [N x K_pad] bf16 (zero-padded K tail)
// ---------------------------------------------------------------------------
__global__ void prep_bt(const float* __restrict__ W, unsigned short* __restrict__ BT,
                        int K, int K_pad, int N)
{
    int idx = blockIdx.x * 256 + threadIdx.x;
    int total = N * K_pad;
    if (idx >= total) return;
    int n = idx / K_pad;
    int k = idx - n * K_pad;
    float v = (k < K) ? W[(size_t)k * N + n] : 0.f;
    BT[idx] = f2bf(v);
}

// ---------------------------------------------------------------------------
// bf16 MFMA GEMM: C[M_pad x 256] = A(fp32, [M_real x K_real]) * B
// with BT = B^T in bf16 [256 x K_pad]. A converted fp32->bf16 during staging.
// 128x128 tile, 256 threads (4 waves, 2x2), 16x16x32 MFMA, 4x4 frags/wave.
// ---------------------------------------------------------------------------
__global__ __launch_bounds__(256)
void gemm_bf16(const float* __restrict__ A, const unsigned short* __restrict__ BT,
               float* __restrict__ C, const float* __restrict__ bias,
               int M_real, int K_real, int K_pad)
{
    __shared__ unsigned short As[128 * 32];   // 8 KB
    __shared__ unsigned short Bs[128 * 32];   // 8 KB
    const int m0 = blockIdx.x * 128;
    const int n0 = blockIdx.y * 128;
    const int t = threadIdx.x;
    const int lane = t & 63;
    const int wave = t >> 6;
    const int wr = (wave >> 1) * 64;
    const int wc = (wave & 1) * 64;
    const int lm = lane & 15;
    const int lk = (lane >> 4) * 8;

    f32x4 acc[4][4];
#pragma unroll
    for (int i = 0; i < 4; i++)
#pragma unroll
        for (int j = 0; j < 4; j++) {
            acc[i][j][0] = 0.f; acc[i][j][1] = 0.f;
            acc[i][j][2] = 0.f; acc[i][j][3] = 0.f;
        }

    const int nkt = K_pad >> 5;
    for (int kt = 0; kt < nkt; ++kt) {
        const int k0 = kt << 5;
        // ---- stage A: 128 rows x 32 cols fp32 -> bf16 in LDS
#pragma unroll
        for (int i = 0; i < 4; i++) {
            int lin = t + (i << 8);          // 0..1023
            int r = lin >> 3;                // 0..127
            int cs = lin & 7;                // 0..7 (4 floats each)
            int row = m0 + r;
            int k = k0 + (cs << 2);
            float v0 = 0.f, v1 = 0.f, v2 = 0.f, v3 = 0.f;
            if (row < M_real) {
                if (k + 4 <= K_real) {
                    const float4 v = *(const float4*)(A + (size_t)row * K_real + k);
                    v0 = v.x; v1 = v.y; v2 = v.z; v3 = v.w;
                } else {
                    const float* ap = A + (size_t)row * K_real;
                    if (k + 0 < K_real) v0 = ap[k + 0];
                    if (k + 1 < K_real) v1 = ap[k + 1];
                    if (k + 2 < K_real) v2 = ap[k + 2];
                    if (k + 3 < K_real) v3 = ap[k + 3];
                }
            }
            uint2 pk;
            pk.x = (unsigned int)f2bf(v0) | ((unsigned int)f2bf(v1) << 16);
            pk.y = (unsigned int)f2bf(v2) | ((unsigned int)f2bf(v3) << 16);
            *(uint2*)&As[r * 32 + (cs << 2)] = pk;
        }
        // ---- stage B: 128 rows (cols of B) x 32 k bf16
#pragma unroll
        for (int i = 0; i < 2; i++) {
            int lin = t + (i << 8);          // 0..511
            int r = lin >> 2;                // 0..127
            int seg = lin & 3;               // 8 bf16 each
            const uint4 v = *(const uint4*)(BT + (size_t)(n0 + r) * K_pad + k0 + (seg << 3));
            *(uint4*)&Bs[r * 32 + (seg << 3)] = v;
        }
        __syncthreads();

        bf16x8 af[4], bfr[4];
#pragma unroll
        for (int i = 0; i < 4; i++)
            af[i] = *(const bf16x8*)&As[(wr + i * 16 + lm) * 32 + lk];
#pragma unroll
        for (int j = 0; j < 4; j++)
            bfr[j] = *(const bf16x8*)&Bs[(wc + j * 16 + lm) * 32 + lk];
#pragma unroll
        for (int i = 0; i < 4; i++)
#pragma unroll
            for (int j = 0; j < 4; j++)
                acc[i][j] = __builtin_amdgcn_mfma_f32_16x16x32_bf16(af[i], bfr[j], acc[i][j], 0, 0, 0);
        __syncthreads();
    }

    // epilogue: C/D layout col=lane&15, row=(lane>>4)*4+reg
    const int lrow = (lane >> 4) * 4;
#pragma unroll
    for (int i = 0; i < 4; i++) {
        int rowb = m0 + wr + i * 16 + lrow;
#pragma unroll
        for (int j = 0; j < 4; j++) {
            int col = n0 + wc + j * 16 + lm;
            float badd = bias ? bias[col] : 0.f;
#pragma unroll
            for (int r = 0; r < 4; r++)
                C[(size_t)(rowb + r) * 256 + col] = acc[i][j][r] + badd;
        }
    }
}

// ---------------------------------------------------------------------------
// CSR build
// ---------------------------------------------------------------------------
__global__ void deg_init(int* __restrict__ deg, int n) {
    int i = blockIdx.x * 256 + threadIdx.x;
    if (i < n) deg[i] = 1;                   // self-loop
}
__global__ void count_kernel(const int* __restrict__ ei, int* __restrict__ deg, int E) {
    int e = blockIdx.x * 256 + threadIdx.x;
    if (e < E) atomicAdd(&deg[ei[E + e]], 1);
}
__global__ void scan_kernel(const int* __restrict__ deg, int* __restrict__ row_start, int n) {
    __shared__ int sm[1024];
    __shared__ int carry;
    int t = threadIdx.x;
    if (t == 0) carry = 0;
    __syncthreads();
    for (int base = 0; base < n; base += 1024) {
        int v = (base + t < n) ? deg[base + t] : 0;
        sm[t] = v;
        __syncthreads();
        for (int off = 1; off < 1024; off <<= 1) {
            int y = (t >= off) ? sm[t - off] : 0;
            __syncthreads();
            sm[t] += y;
            __syncthreads();
        }
        int c = carry;
        if (base + t < n) row_start[base + t] = c + sm[t] - v;   // exclusive
        __syncthreads();
        if (t == 1023) carry = c + sm[1023];
        __syncthreads();
    }
    if (t == 0) row_start[n] = carry;
}
__global__ void selfloop_kernel(const int* __restrict__ row_start, int* __restrict__ cursor,
                                int* __restrict__ nbr, int n) {
    int i = blockIdx.x * 256 + threadIdx.x;
    if (i < n) { int rs = row_start[i]; nbr[rs] = i; cursor[i] = rs + 1; }
}
__global__ void scatter_kernel(const int* __restrict__ ei, int* __restrict__ cursor,
                               int* __restrict__ nbr, int E) {
    int e = blockIdx.x * 256 + threadIdx.x;
    if (e < E) {
        int s = ei[e], d = ei[E + e];
        int pos = atomicAdd(&cursor[d], 1);
        nbr[pos] = s;
    }
}

// ---------------------------------------------------------------------------
// Pooling
// ---------------------------------------------------------------------------
__global__ void batch_count(const int* __restrict__ batch, float* __restrict__ cnt, int n) {
    int i = blockIdx.x * 256 + threadIdx.x;
    if (i < n) atomicAdd(&cnt[batch[i]], 1.f);
}
__global__ void pool_kernel(const float* __restrict__ x, const int* __restrict__ batch,
                            float* __restrict__ sums) {
    int node = blockIdx.x;
    int t = threadIdx.x;
    int b = batch[node];
    atomicAdd(&sums[b * 256 + t], x[(size_t)node * 256 + t]);
}

// ---------------------------------------------------------------------------
// Attention scores: s_src[n,h] = sum_c h[n,h,c]*a_src[h,c]  (one block/node)
// ---------------------------------------------------------------------------
template <int H, int C>
__global__ __launch_bounds__(256)
void attn_scores(const float* __restrict__ hbuf, const float* __restrict__ a_src,
                 const float* __restrict__ a_dst, float* __restrict__ s_src,
                 float* __restrict__ s_dst)
{
    const int node = blockIdx.x;
    const int t = threadIdx.x;
    float hv = hbuf[(size_t)node * 256 + t];
    float ps = hv * a_src[t];
    float pd = hv * a_dst[t];
#pragma unroll
    for (int off = C / 2; off >= 1; off >>= 1) {
        ps += __shfl_down(ps, off, 64);
        pd += __shfl_down(pd, off, 64);
    }
    if ((t & (C - 1)) == 0) {
        s_src[node * H + t / C] = ps;
        s_dst[node * H + t / C] = pd;
    }
}

// ---------------------------------------------------------------------------
// Fused GAT aggregate: online softmax over in-edges + bias + elu + residual + LN
// One block (256 threads = 256 channels) per destination node.
// ---------------------------------------------------------------------------
template <int H, int C>
__global__ __launch_bounds__(256)
void gat_kernel(const float* __restrict__ hbuf, const float* __restrict__ s_src,
                const float* __restrict__ s_dst, const int* __restrict__ row_start,
                const int* __restrict__ nbr, const float* __restrict__ bias,
                const float* __restrict__ gamma, const float* __restrict__ beta,
                const float* __restrict__ x_in, float* __restrict__ x_out)
{
    const int node = blockIdx.x;
    const int t = threadIdx.x;
    const int head = t / C;
    const float sd = s_dst[node * H + head];
    const int beg = row_start[node], end = row_start[node + 1];

    float m = -3.4e38f, z = 0.f, acc = 0.f;
    for (int p = beg; p < end; ++p) {
        int s = nbr[p];
        float e = s_src[s * H + head] + sd;
        e = (e > 0.f) ? e : 0.2f * e;          // leaky_relu 0.2
        float hv = hbuf[(size_t)s * 256 + t];
        float mn = fmaxf(m, e);
        float scale = __expf(m - mn);
        float pe = __expf(e - mn);
        z = z * scale + pe;
        acc = acc * scale + pe * hv;
        m = mn;
    }
    float v = acc / z + bias[t];
    v = (v > 0.f) ? v : (__expf(v) - 1.f);     // elu
    v += x_in[(size_t)node * 256 + t];         // residual

    // LayerNorm over 256 channels
    __shared__ float sbuf[256];
    sbuf[t] = v; __syncthreads();
    for (int s2 = 128; s2 > 0; s2 >>= 1) { if (t < s2) sbuf[t] += sbuf[t + s2]; __syncthreads(); }
    float mu = sbuf[0] * (1.f / 256.f);
    __syncthreads();
    float d = v - mu;
    sbuf[t] = d * d; __syncthreads();
    for (int s2 = 128; s2 > 0; s2 >>= 1) { if (t < s2) sbuf[t] += sbuf[t + s2]; __syncthreads(); }
    float var = sbuf[0] * (1.f / 256.f);
    x_out[(size_t)node * 256 + t] = d * rsqrtf(var + 1e-5f) * gamma[t] + beta[t];
}

// ---------------------------------------------------------------------------
// Head MLP: one block per batch row
// ---------------------------------------------------------------------------
__global__ __launch_bounds__(256)
void mlp_head(const float* __restrict__ xg_sum, const float* __restrict__ xs_sum,
              const float* __restrict__ cnt,
              const float* __restrict__ Wf, const float* __restrict__ bfv,
              const float* __restrict__ Wc1, const float* __restrict__ bc1,
              const float* __restrict__ Wc2, const float* __restrict__ bc2,
              float* __restrict__ out)
{
    const int b = blockIdx.x;
    const int t = threadIdx.x;
    __shared__ float xc[512];
    __shared__ float fs[256];
    __shared__ float gs[128];
    __shared__ float logits[NCLS];
    float c = fmaxf(cnt[b], 1.f);
    xc[t]       = xg_sum[b * 256 + t] / c;
    xc[256 + t] = xs_sum[b * 256 + t] / c;
    __syncthreads();
    float a = bfv[t];
    for (int i = 0; i < 512; i++) a += xc[i] * Wf[i * 256 + t];
    fs[t] = fmaxf(a, 0.f);
    __syncthreads();
    if (t < 128) {
        float a1 = bc1[t];
        for (int i = 0; i < 256; i++) a1 += fs[i] * Wc1[i * 128 + t];
        gs[t] = fmaxf(a1, 0.f);
    }
    __syncthreads();
    if (t < NCLS) {
        float a2 = bc2[t];
        for (int i = 0; i < 128; i++) a2 += gs[i] * Wc2[i * NCLS + t];
        logits[t] = a2;
    }
    __syncthreads();
    if (t < NCLS) {
        float mx = -3.4e38f;
        for (int i = 0; i < NCLS; i++) mx = fmaxf(mx, logits[i]);
        float s = 0.f;
        for (int i = 0; i < NCLS; i++) s += expf(logits[i] - mx);
        out[b * NCLS + t] = logits[t] - mx - logf(s);
    }
}

// ---------------------------------------------------------------------------
extern "C" void kernel_launch(void* const* d_in, const int* in_sizes, int n_in,
                              void* d_out, int out_size, void* d_ws, size_t ws_size,
                              hipStream_t stream)
{
    const float* x      = (const float*)d_in[0];
    const int*   ei     = (const int*)d_in[1];
    const int*   batch  = (const int*)d_in[2];
    const float* W_in   = (const float*)d_in[3];
    const float* b_in   = (const float*)d_in[4];
    const float* W1     = (const float*)d_in[5];
    const float* att_s1 = (const float*)d_in[6];
    const float* att_d1 = (const float*)d_in[7];
    const float* b1     = (const float*)d_in[8];
    const float* g1     = (const float*)d_in[9];
    const float* be1    = (const float*)d_in[10];
    const float* W2     = (const float*)d_in[11];
    const float* att_s2 = (const float*)d_in[12];
    const float* att_d2 = (const float*)d_in[13];
    const float* b2     = (const float*)d_in[14];
    const float* g2     = (const float*)d_in[15];
    const float* be2    = (const float*)d_in[16];
    const float* Wf     = (const float*)d_in[17];
    const float* bfv    = (const float*)d_in[18];
    const float* Wc1    = (const float*)d_in[19];
    const float* bc1    = (const float*)d_in[20];
    const float* Wc2    = (const float*)d_in[21];
    const float* bc2    = (const float*)d_in[22];
    float* out = (float*)d_out;

    char* ws = (char*)d_ws;
    size_t off = 0;
    auto alloc = [&](size_t bytes) -> char* {
        char* p = ws + off;
        off += (bytes + 255) & ~(size_t)255;
        return p;
    };
    float* x0 = (float*)alloc((size_t)M_PAD * 256 * 4);
    float* hb = (float*)alloc((size_t)M_PAD * 256 * 4);
    float* x1 = (float*)alloc((size_t)M_PAD * 256 * 4);
    unsigned short* BTin = (unsigned short*)alloc((size_t)256 * K1_PAD * 2);
    unsigned short* BT1  = (unsigned short*)alloc((size_t)256 * 256 * 2);
    unsigned short* BT2  = (unsigned short*)alloc((size_t)256 * 256 * 2);
    float* s_src = (float*)alloc((size_t)N_NODES * 8 * 4);
    float* s_dst = (float*)alloc((size_t)N_NODES * 8 * 4);
    int* deg       = (int*)alloc((size_t)N_NODES * 4);
    int* row_start = (int*)alloc((size_t)(N_NODES + 1) * 4);
    int* cursor    = (int*)alloc((size_t)N_NODES * 4);
    int* nbr       = (int*)alloc((size_t)(E_EDGES + N_NODES) * 4);
    float* xs_sum  = (float*)alloc(64 * 256 * 4);
    float* xg_sum  = (float*)alloc(64 * 256 * 4);
    float* cnt     = (float*)alloc(64 * 4);
    float* x2 = x0;   // x0 is dead after x1 (x_skip pooled before)

    hipMemsetAsync(xs_sum, 0, 64 * 256 * 4, stream);
    hipMemsetAsync(xg_sum, 0, 64 * 256 * 4, stream);
    hipMemsetAsync(cnt, 0, 64 * 4, stream);

    // weight prep + CSR build
    prep_bt<<<(256 * K1_PAD + 255) / 256, 256, 0, stream>>>(W_in, BTin, V_DIM, K1_PAD, 256);
    prep_bt<<<(256 * 256 + 255) / 256, 256, 0, stream>>>(W1, BT1, 256, 256, 256);
    prep_bt<<<(256 * 256 + 255) / 256, 256, 0, stream>>>(W2, BT2, 256, 256, 256);
    deg_init<<<(N_NODES + 255) / 256, 256, 0, stream>>>(deg, N_NODES);
    count_kernel<<<(E_EDGES + 255) / 256, 256, 0, stream>>>(ei, deg, E_EDGES);
    scan_kernel<<<1, 1024, 0, stream>>>(deg, row_start, N_NODES);
    selfloop_kernel<<<(N_NODES + 255) / 256, 256, 0, stream>>>(row_start, cursor, nbr, N_NODES);
    scatter_kernel<<<(E_EDGES + 255) / 256, 256, 0, stream>>>(ei, cursor, nbr, E_EDGES);
    batch_count<<<(N_NODES + 255) / 256, 256, 0, stream>>>(batch, cnt, N_NODES);

    // input projection + skip pooling
    gemm_bf16<<<dim3(313, 2), 256, 0, stream>>>(x, BTin, x0, b_in, N_NODES, V_DIM, K1_PAD);
    pool_kernel<<<N_NODES, 256, 0, stream>>>(x0, batch, xs_sum);

    // conv1
    gemm_bf16<<<dim3(313, 2), 256, 0, stream>>>(x0, BT1, hb, nullptr, N_NODES, 256, 256);
    attn_scores<8, 32><<<N_NODES, 256, 0, stream>>>(hb, att_s1, att_d1, s_src, s_dst);
    gat_kernel<8, 32><<<N_NODES, 256, 0, stream>>>(hb, s_src, s_dst, row_start, nbr,
                                                   b1, g1, be1, x0, x1);
    // conv2
    gemm_bf16<<<dim3(313, 2), 256, 0, stream>>>(x1, BT2, hb, nullptr, N_NODES, 256, 256);
    attn_scores<4, 64><<<N_NODES, 256, 0, stream>>>(hb, att_s2, att_d2, s_src, s_dst);
    gat_kernel<4, 64><<<N_NODES, 256, 0, stream>>>(hb, s_src, s_dst, row_start, nbr,
                                                   b2, g2, be2, x1, x2);

    // global pooling + head
    pool_kernel<<<N_NODES, 256, 0, stream>>>(x2, batch, xg_sum);
    mlp_head<<<B_BATCH, 256, 0, stream>>>(xg_sum, xs_sum, cnt, Wf, bfv, Wc1, bc1, Wc2, bc2, out);
}